// Round 8
// baseline (79.567 us; speedup 1.0000x reference)
//
#include <hip/hip_runtime.h>
#include <hip/hip_bf16.h>

#define LOG2E 1.4426950408889634f

typedef __attribute__((ext_vector_type(8))) short bf16x8;
typedef __attribute__((ext_vector_type(4))) float f32x4;
typedef __attribute__((ext_vector_type(2))) float v2f;

static __device__ __forceinline__ float fast_exp2(float x) {
    return __builtin_amdgcn_exp2f(x);
}
static __device__ __forceinline__ short bf16bits(float f) {
    __hip_bfloat16 b = __float2bfloat16(f);   // RNE
    return *reinterpret_cast<short*>(&b);
}

__global__ void wconv(const float* __restrict__ W, short* __restrict__ Wb) {
    const int i = blockIdx.x * 256 + threadIdx.x;   // 16384 elems
    Wb[i] = bf16bits(W[i]);
}

// TWO blocks per graph (head-split): block = n*2 + hp, hp selects heads
// hp*16 .. hp*16+15 (= X columns hp*64 .. hp*64+63).
// Phase A: X(64 cols) = h @ W^T via bf16 MFMA (h staged LDS bf16, swizzled).
// Phase B: factorized tables {Es,Fs},{Ed,Fd} = exp2({1,0.2}*logit-halves), f32.
// Phase C: p = max(Ed*Es, Fd*Fs) [== exp2(leaky_relu(ad+as))], 4 dst/lane,
// exact self-edge cancellation.  All-f32 phase C (numerics == round 3).
// LDS 26.4 KB (hsb overlays tables+xs-head, barrier-separated) -> 6 blocks/CU.
template<bool PRE>
__global__ __launch_bounds__(256, 6) void gat_fused(
    const float* __restrict__ hsrc,
    const float* __restrict__ W,
    const short* __restrict__ Wb,
    const float* __restrict__ att_src,
    const float* __restrict__ att_dst,
    const float* __restrict__ bias,
    float* __restrict__ out)
{
    constexpr int A = 50, T = 256, D = 128;
    constexpr int XC = 68;                         // xs col stride (272B: aligned + bank-spread)
    __shared__ __align__(16) char smem[12800 + A * XC * 4];   // 26400 B
    v2f*   tabS = (v2f*)smem;                      // [50*16] {Es,Fs}  (6.4 KB)
    v2f*   tabD = (v2f*)(smem + 6400);             // [50*16] {Ed,Fd}  (6.4 KB)
    float* xs   = (float*)(smem + 12800);          // f32 [50][68], block's 64 cols
    short* hsb  = (short*)smem;                    // overlay: bf16 h [64][128] (phase A only)

    const int bid = blockIdx.x;
    const int n = bid >> 1;                        // graph id
    const int hp = bid & 1;                        // head half: 0 or 1
    const int b = n >> 8;                          // T = 256
    const int t = n & 255;
    const int tid = threadIdx.x;
    const int lane = tid & 63, lr = lane & 15, lg = lane >> 4;
    const int wv = tid >> 6;

    // ---- A1: stage h[b,:,t,:] -> hsb bf16 swizzled (rows 50..63 zero) ----
    const float4* hg4 = (const float4*)hsrc;
    for (int idx = tid; idx < 64 * 32; idx += 256) {
        const int a = idx >> 5, k4 = idx & 31;
        short4 pk = {0, 0, 0, 0};
        if (a < A) {
            const float4 hv = hg4[((size_t)(b * A + a) * T + t) * 32 + k4];
            pk.x = bf16bits(hv.x); pk.y = bf16bits(hv.y);
            pk.z = bf16bits(hv.z); pk.w = bf16bits(hv.w);
        }
        const int swz = (k4 >> 1) ^ (a & 7);       // 16B-chunk swizzle
        *(short4*)&hsb[a * 128 + swz * 8 + (k4 & 1) * 4] = pk;
    }
    __syncthreads();

    // ---- A2: X[:, block's 64 cols] via MFMA; wave owns 16 rows x 64 cols ----
    {
        const int rbase = wv * 16;                 // wave's M rows
        f32x4 acc[4];
        #pragma unroll
        for (int nt = 0; nt < 4; ++nt) acc[nt] = (f32x4){0.f, 0.f, 0.f, 0.f};
        #pragma unroll
        for (int kk = 0; kk < 4; ++kk) {
            const int row = rbase + lr;
            const int chunk = (kk * 4 + lg) ^ (row & 7);
            const bf16x8 af = *(const bf16x8*)&hsb[row * 128 + chunk * 8];
            #pragma unroll
            for (int nt = 0; nt < 4; ++nt) {
                const int e = hp * 64 + nt * 16 + lr;    // W row (output col)
                bf16x8 bf;
                if (PRE) {
                    bf = ((const bf16x8*)Wb)[(size_t)e * 16 + kk * 4 + lg];
                } else {
                    const float4* W4 = (const float4*)W;
                    const int kb = kk * 8 + lg * 2;
                    const float4 wa = W4[(size_t)e * 32 + kb];
                    const float4 wb = W4[(size_t)e * 32 + kb + 1];
                    bf[0] = bf16bits(wa.x); bf[1] = bf16bits(wa.y);
                    bf[2] = bf16bits(wa.z); bf[3] = bf16bits(wa.w);
                    bf[4] = bf16bits(wb.x); bf[5] = bf16bits(wb.y);
                    bf[6] = bf16bits(wb.z); bf[7] = bf16bits(wb.w);
                }
                acc[nt] = __builtin_amdgcn_mfma_f32_16x16x32_bf16(af, bf, acc[nt], 0, 0, 0);
            }
        }
        __syncthreads();   // all hsb reads done before xs (overlapping) is written
        // D layout: row = rbase + lg*4 + r, col_local = nt*16 + lr
        #pragma unroll
        for (int nt = 0; nt < 4; ++nt) {
            #pragma unroll
            for (int r = 0; r < 4; ++r) {
                const int row = rbase + lg * 4 + r;
                if (row < A) xs[row * XC + nt * 16 + lr] = acc[nt][r];
            }
        }
    }
    __syncthreads();

    // ---- B: tables for the block's 16 heads (f32, exact) ----
    for (int p = 0; p < 4; ++p) {
        const int idx = p * 256 + tid;             // = a*16 + hl
        if (idx < A * 16) {
            const int a = idx >> 4, hl = idx & 15;
            const int hg = hp * 16 + hl;
            const float4 xv = *(const float4*)&xs[a * XC + hl * 4];
            const float4 s4 = ((const float4*)att_src)[hg];
            const float4 d4 = ((const float4*)att_dst)[hg];
            const float asc = LOG2E * fmaf(xv.w, s4.w, fmaf(xv.z, s4.z, fmaf(xv.y, s4.y, xv.x * s4.x)));
            const float ads = LOG2E * fmaf(xv.w, d4.w, fmaf(xv.z, d4.z, fmaf(xv.y, d4.y, xv.x * d4.x)));
            tabS[idx] = (v2f){fast_exp2(asc), fast_exp2(0.2f * asc)};
            tabD[idx] = (v2f){fast_exp2(ads), fast_exp2(0.2f * ads)};
        }
    }
    __syncthreads();

    // ---- C: softmax + aggregation; lane owns head hh, 4 dst i = ib + 16r ----
    {
        const int hh = tid & 15;
        const int ib = tid >> 4;                   // 0..15
        const int hg = hp * 16 + hh;
        v2f acc01[4], acc23[4], df[4];
        float l[4];
        #pragma unroll
        for (int r = 0; r < 4; ++r) {
            const int i = ib + 16 * r;
            const int ii = (i < A) ? i : (A - 1);
            df[r] = tabD[ii * 16 + hh];
            acc01[r] = (v2f){0.f, 0.f};
            acc23[r] = (v2f){0.f, 0.f};
            l[r] = 0.f;
        }
        #pragma unroll 5
        for (int j = 0; j < A; ++j) {
            const v2f sf = tabS[j * 16 + hh];
            const float4 xv = *(const float4*)&xs[j * XC + hh * 4];
            const v2f x01 = (v2f){xv.x, xv.y};
            const v2f x23 = (v2f){xv.z, xv.w};
            #pragma unroll
            for (int r = 0; r < 4; ++r) {
                const v2f pe = df[r] * sf;
                const float p = fmaxf(pe.x, pe.y);   // leaky_relu + exp, factorized
                l[r] += p;
                const v2f pp = (v2f){p, p};
                acc01[r] = __builtin_elementwise_fma(pp, x01, acc01[r]);
                acc23[r] = __builtin_elementwise_fma(pp, x23, acc23[r]);
            }
        }
        const float4 bv = ((const float4*)bias)[hg];
        #pragma unroll
        for (int r = 0; r < 4; ++r) {
            const int i = ib + 16 * r;
            if (i < A) {
                // remove self-edge (identical expression -> exact cancellation)
                const v2f sf = tabS[i * 16 + hh];
                const float4 xv = *(const float4*)&xs[i * XC + hh * 4];
                const v2f pe = df[r] * sf;
                const float p = fmaxf(pe.x, pe.y);
                const float linv = 1.0f / (l[r] - p);
                float4 o;
                o.x = fmaf(acc01[r].x - p * xv.x, linv, bv.x);
                o.y = fmaf(acc01[r].y - p * xv.y, linv, bv.y);
                o.z = fmaf(acc23[r].x - p * xv.z, linv, bv.z);
                o.w = fmaf(acc23[r].y - p * xv.w, linv, bv.w);
                *(float4*)&out[((size_t)(b * A + i) * T + t) * D + hg * 4] = o;
            }
        }
    }
}

extern "C" void kernel_launch(void* const* d_in, const int* in_sizes, int n_in,
                              void* d_out, int out_size, void* d_ws, size_t ws_size,
                              hipStream_t stream) {
    const float* h       = (const float*)d_in[0];
    const float* W       = (const float*)d_in[1];
    const float* att_src = (const float*)d_in[2];
    const float* att_dst = (const float*)d_in[3];
    const float* bias    = (const float*)d_in[4];
    float* out = (float*)d_out;
    dim3 grid(8 * 256 * 2);   // 2 blocks per graph (head halves)
    dim3 block(256);
    if (ws_size >= 128 * 128 * sizeof(short)) {
        short* Wb = (short*)d_ws;
        hipLaunchKernelGGL(wconv, dim3(64), block, 0, stream, W, Wb);
        hipLaunchKernelGGL(gat_fused<true>, grid, block, 0, stream,
                           h, W, Wb, att_src, att_dst, bias, out);
    } else {
        hipLaunchKernelGGL(gat_fused<false>, grid, block, 0, stream,
                           h, W, (const short*)nullptr, att_src, att_dst, bias, out);
    }
}

// Round 9
// 59.540 us; speedup vs baseline: 1.3364x; 1.3364x over previous
//
#include <hip/hip_runtime.h>
#include <hip/hip_bf16.h>

#define LOG2E 1.4426950408889634f

typedef __attribute__((ext_vector_type(8))) short bf16x8;
typedef __attribute__((ext_vector_type(4))) float f32x4;
typedef __attribute__((ext_vector_type(2))) float v2f;

static __device__ __forceinline__ float fast_exp2(float x) {
    return __builtin_amdgcn_exp2f(x);
}
static __device__ __forceinline__ short bf16bits(float f) {
    __hip_bfloat16 b = __float2bfloat16(f);   // RNE
    return *reinterpret_cast<short*>(&b);
}
static __device__ __forceinline__ float bfbits2f(unsigned lo16) {
    return __uint_as_float(lo16 << 16);
}

__global__ void wconv(const float* __restrict__ W, short* __restrict__ Wb) {
    const int i = blockIdx.x * 256 + threadIdx.x;   // 16384 elems
    Wb[i] = bf16bits(W[i]);
}

// One block per graph n = b*T + t.  A=50 nodes, D=128, H=32 heads, C=4.
// LDS entry cxs[a][hh] (16B): {x0x1 bf16x2, x2x3 bf16x2, Es f32, Fs f32}
//   -> phase C does ONE ds_read_b128 per j (sf = .zw directly, x unpack 4 ops).
// Phase A: X = h @ W^T via bf16 MFMA (h staged LDS bf16 swizzled, overlaid by cxs);
//          epilogue writes X bf16 into entry .xy via ds_write_b16.
// Phase B: logits from entry .xy; writes {Es,Fs}=exp2({1,.2}asc) to .zw,
//          {Ed,Fd} to separate table.
// Phase C: p = max(Ed*Es, Fd*Fs) [= exp2(leaky_relu(ad+as))], 7 dst/lane,
//          1-deep prefetch pipeline, exact self-edge cancellation.
// LDS 39424 B -> 4 blocks/CU.
template<bool PRE>
__global__ __launch_bounds__(256, 4) void gat_fused(
    const float* __restrict__ hsrc,
    const float* __restrict__ W,
    const short* __restrict__ Wb,
    const float* __restrict__ att_src,
    const float* __restrict__ att_dst,
    const float* __restrict__ bias,
    float* __restrict__ out)
{
    constexpr int A = 50, T = 256, D = 128, H = 32;
    __shared__ __align__(16) char smem[52 * 32 * 16 + A * H * 8];  // 26624 + 12800
    char*  cxs  = smem;                            // [52][32] 16B entries
    v2f*   EdFd = (v2f*)(smem + 26624);            // [A*H] {Ed, Fd}
    short* hsb  = (short*)smem;                    // overlay: bf16 h [64][128] (phase A only)

    const int n = blockIdx.x;
    const int b = n >> 8;                          // T = 256
    const int t = n & 255;
    const int tid = threadIdx.x;
    const int lane = tid & 63, lr = lane & 15, lg = lane >> 4;
    const int wv = tid >> 6;

    // ---- A1: stage h[b,:,t,:] -> hsb bf16 swizzled (rows 50..63 zero) ----
    const float4* hg4 = (const float4*)hsrc;
    for (int idx = tid; idx < 64 * 32; idx += 256) {
        const int a = idx >> 5, k4 = idx & 31;
        short4 pk = {0, 0, 0, 0};
        if (a < A) {
            const float4 hv = hg4[((size_t)(b * A + a) * T + t) * 32 + k4];
            pk.x = bf16bits(hv.x); pk.y = bf16bits(hv.y);
            pk.z = bf16bits(hv.z); pk.w = bf16bits(hv.w);
        }
        const int swz = (k4 >> 1) ^ (a & 7);       // 16B-chunk swizzle
        *(short4*)&hsb[a * 128 + swz * 8 + (k4 & 1) * 4] = pk;
    }
    __syncthreads();

    // ---- A2: X = h @ W^T (MFMA 16x16x32 bf16); wave owns 32 output cols ----
    {
        const int n0 = wv * 32;
        f32x4 acc[4][2];
        #pragma unroll
        for (int m = 0; m < 4; ++m) {
            acc[m][0] = (f32x4){0.f, 0.f, 0.f, 0.f};
            acc[m][1] = (f32x4){0.f, 0.f, 0.f, 0.f};
        }
        #pragma unroll
        for (int kk = 0; kk < 4; ++kk) {
            bf16x8 bf0, bf1;
            if (PRE) {
                const bf16x8* Wb8 = (const bf16x8*)Wb;
                bf0 = Wb8[(size_t)(n0 + lr) * 16 + kk * 4 + lg];
                bf1 = Wb8[(size_t)(n0 + 16 + lr) * 16 + kk * 4 + lg];
            } else {
                const float4* W4 = (const float4*)W;
                const int kb = kk * 8 + lg * 2;
                const float4 wa = W4[(size_t)(n0 + lr) * 32 + kb];
                const float4 wb = W4[(size_t)(n0 + lr) * 32 + kb + 1];
                const float4 wc = W4[(size_t)(n0 + 16 + lr) * 32 + kb];
                const float4 wd = W4[(size_t)(n0 + 16 + lr) * 32 + kb + 1];
                bf0[0] = bf16bits(wa.x); bf0[1] = bf16bits(wa.y);
                bf0[2] = bf16bits(wa.z); bf0[3] = bf16bits(wa.w);
                bf0[4] = bf16bits(wb.x); bf0[5] = bf16bits(wb.y);
                bf0[6] = bf16bits(wb.z); bf0[7] = bf16bits(wb.w);
                bf1[0] = bf16bits(wc.x); bf1[1] = bf16bits(wc.y);
                bf1[2] = bf16bits(wc.z); bf1[3] = bf16bits(wc.w);
                bf1[4] = bf16bits(wd.x); bf1[5] = bf16bits(wd.y);
                bf1[6] = bf16bits(wd.z); bf1[7] = bf16bits(wd.w);
            }
            #pragma unroll
            for (int m = 0; m < 4; ++m) {
                const int row = m * 16 + lr;
                const int chunk = (kk * 4 + lg) ^ (row & 7);
                const bf16x8 af = *(const bf16x8*)&hsb[row * 128 + chunk * 8];
                acc[m][0] = __builtin_amdgcn_mfma_f32_16x16x32_bf16(af, bf0, acc[m][0], 0, 0, 0);
                acc[m][1] = __builtin_amdgcn_mfma_f32_16x16x32_bf16(af, bf1, acc[m][1], 0, 0, 0);
            }
        }
        __syncthreads();   // all hsb reads complete before cxs (overlay) is written
        // D layout: row = m*16 + lg*4 + r, col = n0 + nt*16 + lr.
        // Write X bf16 into entry .xy: byte = (row*32 + col/4)*16 + (col%4)*2
        #pragma unroll
        for (int m = 0; m < 4; ++m) {
            #pragma unroll
            for (int nt = 0; nt < 2; ++nt) {
                const int col = n0 + nt * 16 + lr;
                const int boff = (col >> 2) * 16 + (col & 3) * 2;
                #pragma unroll
                for (int r = 0; r < 4; ++r) {
                    const int row = m * 16 + lg * 4 + r;
                    if (row < 52)   // rows 50,51 = zeros (prefetch pad)
                        *(short*)&cxs[row * 512 + boff] = bf16bits(acc[m][nt][r]);
                }
            }
        }
    }
    __syncthreads();

    // ---- B: logits + factorized exp tables; fill entry .zw and EdFd ----
    for (int idx = tid; idx < A * H; idx += 256) {
        const int hh = idx & 31;
        const uint2 xq = *(const uint2*)&cxs[idx * 16];
        const float x0 = bfbits2f(xq.x & 0xffffu);
        const float x1 = __uint_as_float(xq.x & 0xffff0000u);
        const float x2 = bfbits2f(xq.y & 0xffffu);
        const float x3 = __uint_as_float(xq.y & 0xffff0000u);
        const float4 s4 = ((const float4*)att_src)[hh];
        const float4 d4 = ((const float4*)att_dst)[hh];
        const float asc = LOG2E * fmaf(x3, s4.w, fmaf(x2, s4.z, fmaf(x1, s4.y, x0 * s4.x)));
        const float ads = LOG2E * fmaf(x3, d4.w, fmaf(x2, d4.z, fmaf(x1, d4.y, x0 * d4.x)));
        *(v2f*)&cxs[idx * 16 + 8] = (v2f){fast_exp2(asc), fast_exp2(0.2f * asc)};
        EdFd[idx] = (v2f){fast_exp2(ads), fast_exp2(0.2f * ads)};
    }
    __syncthreads();

    // ---- C: softmax + aggregation; lane owns head hh, 7 dst i = ib + 8r ----
    {
        const int hh = tid & 31;
        const int ib = tid >> 5;                    // 0..7
        v2f acc01[7], acc23[7], df[7];
        float l[7];
        #pragma unroll
        for (int r = 0; r < 7; ++r) {
            const int i = ib + 8 * r;
            const int ii = (i < A) ? i : (A - 1);
            df[r] = EdFd[ii * H + hh];
            acc01[r] = (v2f){0.f, 0.f};
            acc23[r] = (v2f){0.f, 0.f};
            l[r] = 0.f;
        }
        const char* cp = &cxs[hh * 16];
        uint4 cur = *(const uint4*)cp;              // entry (j=0, hh)
        #pragma unroll 2
        for (int j = 0; j < A; ++j) {
            const uint4 nxt = *(const uint4*)(cp + (j + 1) * 512);  // row 50 pad: safe
            const v2f sf = (v2f){__uint_as_float(cur.z), __uint_as_float(cur.w)};
            const v2f x01 = (v2f){bfbits2f(cur.x & 0xffffu),
                                  __uint_as_float(cur.x & 0xffff0000u)};
            const v2f x23 = (v2f){bfbits2f(cur.y & 0xffffu),
                                  __uint_as_float(cur.y & 0xffff0000u)};
            #pragma unroll
            for (int r = 0; r < 7; ++r) {
                const v2f pe = df[r] * sf;                       // v_pk_mul_f32
                const float p = fmaxf(pe.x, pe.y);               // leaky+exp, factorized
                l[r] += p;
                const v2f pp = (v2f){p, p};
                acc01[r] = __builtin_elementwise_fma(pp, x01, acc01[r]);
                acc23[r] = __builtin_elementwise_fma(pp, x23, acc23[r]);
            }
            cur = nxt;
        }
        const float4 bv = ((const float4*)bias)[hh];
        #pragma unroll
        for (int r = 0; r < 7; ++r) {
            const int i = ib + 8 * r;
            if (i < A) {
                // remove self-edge (identical expression -> exact cancellation)
                const uint4 ce = *(const uint4*)&cxs[(i * 32 + hh) * 16];
                const v2f sf = (v2f){__uint_as_float(ce.z), __uint_as_float(ce.w)};
                const float xx0 = bfbits2f(ce.x & 0xffffu);
                const float xx1 = __uint_as_float(ce.x & 0xffff0000u);
                const float xx2 = bfbits2f(ce.y & 0xffffu);
                const float xx3 = __uint_as_float(ce.y & 0xffff0000u);
                const v2f pe = df[r] * sf;
                const float p = fmaxf(pe.x, pe.y);
                const float linv = 1.0f / (l[r] - p);
                float4 o;
                o.x = fmaf(acc01[r].x - p * xx0, linv, bv.x);
                o.y = fmaf(acc01[r].y - p * xx1, linv, bv.y);
                o.z = fmaf(acc23[r].x - p * xx2, linv, bv.z);
                o.w = fmaf(acc23[r].y - p * xx3, linv, bv.w);
                *(float4*)&out[((size_t)(b * A + i) * T + t) * D + hh * 4] = o;
            }
        }
    }
}

extern "C" void kernel_launch(void* const* d_in, const int* in_sizes, int n_in,
                              void* d_out, int out_size, void* d_ws, size_t ws_size,
                              hipStream_t stream) {
    const float* h       = (const float*)d_in[0];
    const float* W       = (const float*)d_in[1];
    const float* att_src = (const float*)d_in[2];
    const float* att_dst = (const float*)d_in[3];
    const float* bias    = (const float*)d_in[4];
    float* out = (float*)d_out;
    dim3 grid(8 * 256);   // B*T graphs
    dim3 block(256);
    if (ws_size >= 128 * 128 * sizeof(short)) {
        short* Wb = (short*)d_ws;
        hipLaunchKernelGGL(wconv, dim3(64), block, 0, stream, W, Wb);
        hipLaunchKernelGGL(gat_fused<true>, grid, block, 0, stream,
                           h, W, Wb, att_src, att_dst, bias, out);
    } else {
        hipLaunchKernelGGL(gat_fused<false>, grid, block, 0, stream,
                           h, W, (const short*)nullptr, att_src, att_dst, bias, out);
    }
}